// Round 11
// baseline (29.257 us; speedup 1.0000x reference)
//
#include <hip/hip_runtime.h>

#define NROWS 4096
#define DIM 128
#define PCLS 1024
#define NPAIR 6144
#define MARGIN 1.0f
#define EPS 1e-6f
#define LOG2E 1.4426950408889634f
#define NSPLIT 32

typedef __attribute__((ext_vector_type(8))) short bf16x8;
typedef __attribute__((ext_vector_type(4))) float f32x4;

union FragU { uint4 u; bf16x8 v; unsigned short us[8]; };

__device__ __forceinline__ unsigned short f2bf(float f) {
    unsigned int b = __float_as_uint(f);
    b = (b + 0x7FFFu + ((b >> 16) & 1u)) >> 16;
    return (unsigned short)b;
}
__device__ __forceinline__ float bf2f(unsigned short u) {
    return __uint_as_float((unsigned int)u << 16);
}

// Fused prep+main, high-occupancy variant: 128-col B-panel (32 KB LDS) ->
// 4 blocks/CU, 32 waves/CU (launch_bounds(512,8), VGPR<=64).
// grid: 32 row-blocks (128 rows) x 32 col-splits (128 cols) = 1024 blocks.
__launch_bounds__(512, 8)
__global__ void main_kernel(const float* __restrict__ x,
                            unsigned short* __restrict__ partial,
                            float* __restrict__ posD) {
    __shared__ __align__(16) unsigned short lds[128 * DIM]; // 32 KB bf16 B-panel
    __shared__ float normRow[128];
    __shared__ float normCol[128];
    const int t = threadIdx.x;
    const int w = t >> 6;
    const int l = t & 63;
    const int rb = blockIdx.x >> 5;
    const int cs = blockIdx.x & 31;
    const int rbase = rb * 128 + w * 16;   // this wave's 16 rows
    const int cbase = cs * 128;
    const int lg = l >> 4;                 // k-group (0..3)
    const int lr = l & 15;                 // frag row/col index

    // ---- A fragments (16 rows x 128 k): f32 load + convert; row norms fused.
    FragU afr[4];
    float rn = 0.f;
    const float* arow = x + (size_t)(rbase + lr) * DIM + lg * 8;
    #pragma unroll
    for (int s = 0; s < 4; ++s) {
        float4 a0 = *reinterpret_cast<const float4*>(arow + s * 32);
        float4 a1 = *reinterpret_cast<const float4*>(arow + s * 32 + 4);
        afr[s].us[0] = f2bf(a0.x); afr[s].us[1] = f2bf(a0.y);
        afr[s].us[2] = f2bf(a0.z); afr[s].us[3] = f2bf(a0.w);
        afr[s].us[4] = f2bf(a1.x); afr[s].us[5] = f2bf(a1.y);
        afr[s].us[6] = f2bf(a1.z); afr[s].us[7] = f2bf(a1.w);
        rn = fmaf(a0.x, a0.x, rn); rn = fmaf(a0.y, a0.y, rn);
        rn = fmaf(a0.z, a0.z, rn); rn = fmaf(a0.w, a0.w, rn);
        rn = fmaf(a1.x, a1.x, rn); rn = fmaf(a1.y, a1.y, rn);
        rn = fmaf(a1.z, a1.z, rn); rn = fmaf(a1.w, a1.w, rn);
    }
    rn += __shfl_xor(rn, 16, 64);          // reduce across lg
    rn += __shfl_xor(rn, 32, 64);
    if (lg == 0) normRow[w * 16 + lr] = rn;

    // ---- B-panel staging (128 cols x 128 k) f32 -> bf16, XOR-swizzled,
    //      col norms fused (each 16-lane group stages one full column/iter)
    #pragma unroll
    for (int q = 0; q < 4; ++q) {
        int col = q * 32 + (t >> 4);       // 0..127
        int if32 = (t & 15) * 8;           // f32 offset within column
        const float* bp = x + (size_t)(cbase + col) * DIM + if32;
        float4 b0 = *reinterpret_cast<const float4*>(bp);
        float4 b1 = *reinterpret_cast<const float4*>(bp + 4);
        FragU h;
        h.us[0] = f2bf(b0.x); h.us[1] = f2bf(b0.y);
        h.us[2] = f2bf(b0.z); h.us[3] = f2bf(b0.w);
        h.us[4] = f2bf(b1.x); h.us[5] = f2bf(b1.y);
        h.us[6] = f2bf(b1.z); h.us[7] = f2bf(b1.w);
        int ib = if32 * 2;                 // byte offset, multiple of 16
        *reinterpret_cast<uint4*>(
            (char*)lds + col * 256 + (ib ^ ((col & 7) << 4))) = h.u;
        float cn = 0.f;
        cn = fmaf(b0.x, b0.x, cn); cn = fmaf(b0.y, b0.y, cn);
        cn = fmaf(b0.z, b0.z, cn); cn = fmaf(b0.w, b0.w, cn);
        cn = fmaf(b1.x, b1.x, cn); cn = fmaf(b1.y, b1.y, cn);
        cn = fmaf(b1.z, b1.z, cn); cn = fmaf(b1.w, b1.w, cn);
        cn += __shfl_xor(cn, 1, 64);
        cn += __shfl_xor(cn, 2, 64);
        cn += __shfl_xor(cn, 4, 64);
        cn += __shfl_xor(cn, 8, 64);
        if ((t & 15) == 0) normCol[col] = cn;
    }

    __syncthreads();

    // per-lane norms from LDS
    float njv[8];
    #pragma unroll
    for (int tile = 0; tile < 8; ++tile)
        njv[tile] = normCol[tile * 16 + lr];
    float ni[4];
    #pragma unroll
    for (int rr = 0; rr < 4; ++rr)
        ni[rr] = normRow[w * 16 + lg * 4 + rr] + EPS;  // fold +EPS

    float accS[4] = {0.f, 0.f, 0.f, 0.f};

    #pragma unroll
    for (int tile = 0; tile < 8; ++tile) {
        const int lcol = tile * 16 + lr;
        const float nj = njv[tile];
        const char* bbase = (const char*)lds + lcol * 256;
        const int xr = (lcol & 7) << 4;
        f32x4 acc = {0.f, 0.f, 0.f, 0.f};
        #pragma unroll
        for (int s = 0; s < 4; ++s) {
            FragU bu;
            int inner = s * 64 + lg * 16;
            bu.u = *reinterpret_cast<const uint4*>(bbase + (inner ^ xr));
            acc = __builtin_amdgcn_mfma_f32_16x16x32_bf16(afr[s].v, bu.v, acc, 0, 0, 0);
        }
        const bool diag = (cbase + tile * 16) == rbase;  // wave-uniform
        if (!diag) {
            #pragma unroll
            for (int rr = 0; rr < 4; ++rr) {
                float nn = ni[rr] + nj;
                float d2 = fmaf(-2.0f, acc[rr], nn);
                float d = __builtin_amdgcn_sqrtf(fmaxf(d2, EPS));
                accS[rr] += __builtin_amdgcn_exp2f(fmaf(d, -LOG2E, LOG2E));
            }
        } else {
            // diagonal 16x16 tile: same-class masking + positive-pair extraction
            #pragma unroll
            for (int rr = 0; rr < 4; ++rr) {
                int a = lg * 4 + rr;               // local row 0..15
                int b = lr;                        // local col 0..15
                float nn = ni[rr] + nj;
                float d2 = fmaf(-2.0f, acc[rr], nn);
                float d = __builtin_amdgcn_sqrtf(fmaxf(d2, EPS));
                float e = __builtin_amdgcn_exp2f(fmaf(d, -LOG2E, LOG2E));
                bool same = (a >> 2) == (b >> 2);
                accS[rr] += same ? 0.f : e;
                if (same && a < b) {
                    int i = a & 3, j = b & 3;
                    int idx = i * (7 - i) / 2 + (j - i - 1);
                    int cls = (rbase + a) >> 2;
                    posD[cls * 6 + idx] = d;
                }
            }
        }
    }
    // reduce over the 16 col-lanes
    #pragma unroll
    for (int rr = 0; rr < 4; ++rr) {
        #pragma unroll
        for (int m = 1; m < 16; m <<= 1) accS[rr] += __shfl_xor(accS[rr], m, 64);
    }
    if (lr == 0) {
        #pragma unroll
        for (int rr = 0; rr < 4; ++rr)
            partial[cs * NROWS + rbase + lg * 4 + rr] = f2bf(accS[rr]);
    }
}

// single block: S = sum of 32 bf16 split panels, J per pair, relu^2, mean
__global__ void tail_kernel(const unsigned short* __restrict__ partial,
                            const float* __restrict__ posD,
                            float* __restrict__ out) {
    const int c = threadIdx.x;    // class 0..1023
    float S[4] = {0.f, 0.f, 0.f, 0.f};
    #pragma unroll
    for (int sp = 0; sp < NSPLIT; ++sp) {
        ushort4 v = *reinterpret_cast<const ushort4*>(partial + sp * NROWS + 4 * c);
        S[0] += bf2f(v.x); S[1] += bf2f(v.y); S[2] += bf2f(v.z); S[3] += bf2f(v.w);
    }
    const int II[6] = {0, 0, 0, 1, 1, 2};
    const int JJ[6] = {1, 2, 3, 2, 3, 3};
    float acc = 0.f;
    #pragma unroll
    for (int p = 0; p < 6; ++p) {
        float d = posD[c * 6 + p];
        float J = __logf(S[II[p]] + S[JJ[p]]) + d;
        float r = fmaxf(J, 0.f);
        acc += r * r;
    }
    // block reduce 1024 -> 1
    #pragma unroll
    for (int m = 1; m < 64; m <<= 1) acc += __shfl_xor(acc, m, 64);
    __shared__ float red[16];
    if ((c & 63) == 0) red[c >> 6] = acc;
    __syncthreads();
    if (c < 64) {
        float v = (c < 16) ? red[c] : 0.f;
        #pragma unroll
        for (int m = 1; m < 16; m <<= 1) v += __shfl_xor(v, m, 64);
        if (c == 0) out[0] = v * (1.0f / (2.0f * (float)NPAIR));
    }
}

extern "C" void kernel_launch(void* const* d_in, const int* in_sizes, int n_in,
                              void* d_out, int out_size, void* d_ws, size_t ws_size,
                              hipStream_t stream) {
    const float* x = (const float*)d_in[0];
    char* ws = (char*)d_ws;
    unsigned short* partial = (unsigned short*)ws;        // 32*4096 bf16 = 256 KB
    float* posD = (float*)(ws + 262144);                  // 24 KB
    float* out = (float*)d_out;

    hipLaunchKernelGGL(main_kernel, dim3(1024), dim3(512), 0, stream, x, partial, posD);
    hipLaunchKernelGGL(tail_kernel, dim3(1), dim3(1024), 0, stream, partial, posD, out);
}

// Round 12
// 23.377 us; speedup vs baseline: 1.2515x; 1.2515x over previous
//
#include <hip/hip_runtime.h>

#define NROWS 4096
#define DIM 128
#define PCLS 1024
#define NPAIR 6144
#define MARGIN 1.0f
#define EPS 1e-6f
#define LOG2E 1.4426950408889634f
#define NSPLIT 16

typedef __attribute__((ext_vector_type(8))) short bf16x8;
typedef __attribute__((ext_vector_type(4))) float f32x4;

union FragU { uint4 u; bf16x8 v; unsigned short us[8]; };

__device__ __forceinline__ unsigned short f2bf(float f) {
    unsigned int b = __float_as_uint(f);
    b = (b + 0x7FFFu + ((b >> 16) & 1u)) >> 16;
    return (unsigned short)b;
}
__device__ __forceinline__ float bf2f(unsigned short u) {
    return __uint_as_float((unsigned int)u << 16);
}

// Fused prep+main: f32 -> bf16 conversion, norms (f32-exact, folded into the
// A-frag loads and B-staging loop at zero extra global reads), Gram tiles via
// bf16 MFMA, exp epilogue, positive-pair extraction.
// grid: 32 row-blocks (128 rows) x 16 col-splits (256 cols) = 512 blocks, 512 thr.
__launch_bounds__(512, 4)
__global__ void main_kernel(const float* __restrict__ x,
                            unsigned short* __restrict__ partial,
                            float* __restrict__ posD) {
    __shared__ __align__(16) unsigned short lds[256 * DIM]; // 64 KB bf16 B-panel
    __shared__ float normRow[128];
    __shared__ float normCol[256];
    const int t = threadIdx.x;
    const int w = t >> 6;
    const int l = t & 63;
    const int rb = blockIdx.x >> 4;
    const int cs = blockIdx.x & 15;
    const int rbase = rb * 128 + w * 16;   // this wave's 16 rows
    const int cbase = cs * 256;
    const int lg = l >> 4;                 // k-group (0..3)
    const int lr = l & 15;                 // frag row/col index

    // ---- A fragments (16 rows x 128 k): f32 load + convert; row norms fused.
    // lane (lg,lr) holds row rbase+lr, k in [s*32+lg*8, +8)
    FragU afr[4];
    float rn = 0.f;
    const float* arow = x + (size_t)(rbase + lr) * DIM + lg * 8;
    #pragma unroll
    for (int s = 0; s < 4; ++s) {
        float4 a0 = *reinterpret_cast<const float4*>(arow + s * 32);
        float4 a1 = *reinterpret_cast<const float4*>(arow + s * 32 + 4);
        afr[s].us[0] = f2bf(a0.x); afr[s].us[1] = f2bf(a0.y);
        afr[s].us[2] = f2bf(a0.z); afr[s].us[3] = f2bf(a0.w);
        afr[s].us[4] = f2bf(a1.x); afr[s].us[5] = f2bf(a1.y);
        afr[s].us[6] = f2bf(a1.z); afr[s].us[7] = f2bf(a1.w);
        rn = fmaf(a0.x, a0.x, rn); rn = fmaf(a0.y, a0.y, rn);
        rn = fmaf(a0.z, a0.z, rn); rn = fmaf(a0.w, a0.w, rn);
        rn = fmaf(a1.x, a1.x, rn); rn = fmaf(a1.y, a1.y, rn);
        rn = fmaf(a1.z, a1.z, rn); rn = fmaf(a1.w, a1.w, rn);
    }
    rn += __shfl_xor(rn, 16, 64);          // reduce across lg
    rn += __shfl_xor(rn, 32, 64);
    if (lg == 0) normRow[w * 16 + lr] = rn;

    // ---- B-panel staging (256 cols x 128 k) f32 -> bf16, XOR-swizzled,
    //      col norms fused (each 16-lane group stages one full column/iter)
    #pragma unroll
    for (int q = 0; q < 8; ++q) {
        int col = q * 32 + (t >> 4);       // 0..255, each col once overall
        int if32 = (t & 15) * 8;           // f32 offset within column
        const float* bp = x + (size_t)(cbase + col) * DIM + if32;
        float4 b0 = *reinterpret_cast<const float4*>(bp);
        float4 b1 = *reinterpret_cast<const float4*>(bp + 4);
        FragU h;
        h.us[0] = f2bf(b0.x); h.us[1] = f2bf(b0.y);
        h.us[2] = f2bf(b0.z); h.us[3] = f2bf(b0.w);
        h.us[4] = f2bf(b1.x); h.us[5] = f2bf(b1.y);
        h.us[6] = f2bf(b1.z); h.us[7] = f2bf(b1.w);
        int ib = if32 * 2;                 // byte offset, multiple of 16
        *reinterpret_cast<uint4*>(
            (char*)lds + col * 256 + (ib ^ ((col & 7) << 4))) = h.u;
        float cn = 0.f;
        cn = fmaf(b0.x, b0.x, cn); cn = fmaf(b0.y, b0.y, cn);
        cn = fmaf(b0.z, b0.z, cn); cn = fmaf(b0.w, b0.w, cn);
        cn = fmaf(b1.x, b1.x, cn); cn = fmaf(b1.y, b1.y, cn);
        cn = fmaf(b1.z, b1.z, cn); cn = fmaf(b1.w, b1.w, cn);
        cn += __shfl_xor(cn, 1, 64);
        cn += __shfl_xor(cn, 2, 64);
        cn += __shfl_xor(cn, 4, 64);
        cn += __shfl_xor(cn, 8, 64);
        if ((t & 15) == 0) normCol[col] = cn;
    }

    __syncthreads();

    // per-lane norms from LDS (njv: same addr across lg -> broadcast)
    float njv[16];
    #pragma unroll
    for (int tile = 0; tile < 16; ++tile)
        njv[tile] = normCol[tile * 16 + lr];
    float ni[4];
    #pragma unroll
    for (int rr = 0; rr < 4; ++rr)
        ni[rr] = normRow[w * 16 + lg * 4 + rr] + EPS;  // fold +EPS

    float accS[4] = {0.f, 0.f, 0.f, 0.f};

    #pragma unroll
    for (int tile = 0; tile < 16; ++tile) {
        const int lcol = tile * 16 + lr;
        const float nj = njv[tile];
        const char* bbase = (const char*)lds + lcol * 256;
        const int xr = (lcol & 7) << 4;
        f32x4 acc = {0.f, 0.f, 0.f, 0.f};
        #pragma unroll
        for (int s = 0; s < 4; ++s) {
            FragU bu;
            int inner = s * 64 + lg * 16;
            bu.u = *reinterpret_cast<const uint4*>(bbase + (inner ^ xr));
            acc = __builtin_amdgcn_mfma_f32_16x16x32_bf16(afr[s].v, bu.v, acc, 0, 0, 0);
        }
        const bool diag = (cbase + tile * 16) == rbase;  // wave-uniform
        if (!diag) {
            #pragma unroll
            for (int rr = 0; rr < 4; ++rr) {
                float nn = ni[rr] + nj;
                float d2 = fmaf(-2.0f, acc[rr], nn);
                float d = __builtin_amdgcn_sqrtf(fmaxf(d2, EPS));
                accS[rr] += __builtin_amdgcn_exp2f(fmaf(d, -LOG2E, LOG2E));
            }
        } else {
            // diagonal 16x16 tile: same-class masking + positive-pair extraction
            #pragma unroll
            for (int rr = 0; rr < 4; ++rr) {
                int a = lg * 4 + rr;               // local row 0..15
                int b = lr;                        // local col 0..15
                float nn = ni[rr] + nj;
                float d2 = fmaf(-2.0f, acc[rr], nn);
                float d = __builtin_amdgcn_sqrtf(fmaxf(d2, EPS));
                float e = __builtin_amdgcn_exp2f(fmaf(d, -LOG2E, LOG2E));
                bool same = (a >> 2) == (b >> 2);
                accS[rr] += same ? 0.f : e;
                if (same && a < b) {
                    int i = a & 3, j = b & 3;
                    int idx = i * (7 - i) / 2 + (j - i - 1);
                    int cls = (rbase + a) >> 2;
                    posD[cls * 6 + idx] = d;
                }
            }
        }
    }
    // reduce over the 16 col-lanes
    #pragma unroll
    for (int rr = 0; rr < 4; ++rr) {
        #pragma unroll
        for (int m = 1; m < 16; m <<= 1) accS[rr] += __shfl_xor(accS[rr], m, 64);
    }
    if (lr == 0) {
        #pragma unroll
        for (int rr = 0; rr < 4; ++rr)
            partial[cs * NROWS + rbase + lg * 4 + rr] = f2bf(accS[rr]);
    }
}

// single block: S = sum of 16 bf16 split panels, J per pair, relu^2, mean
__global__ void tail_kernel(const unsigned short* __restrict__ partial,
                            const float* __restrict__ posD,
                            float* __restrict__ out) {
    const int c = threadIdx.x;    // class 0..1023
    float S[4] = {0.f, 0.f, 0.f, 0.f};
    #pragma unroll
    for (int sp = 0; sp < NSPLIT; ++sp) {
        ushort4 v = *reinterpret_cast<const ushort4*>(partial + sp * NROWS + 4 * c);
        S[0] += bf2f(v.x); S[1] += bf2f(v.y); S[2] += bf2f(v.z); S[3] += bf2f(v.w);
    }
    const int II[6] = {0, 0, 0, 1, 1, 2};
    const int JJ[6] = {1, 2, 3, 2, 3, 3};
    float acc = 0.f;
    #pragma unroll
    for (int p = 0; p < 6; ++p) {
        float d = posD[c * 6 + p];
        float J = __logf(S[II[p]] + S[JJ[p]]) + d;
        float r = fmaxf(J, 0.f);
        acc += r * r;
    }
    // block reduce 1024 -> 1
    #pragma unroll
    for (int m = 1; m < 64; m <<= 1) acc += __shfl_xor(acc, m, 64);
    __shared__ float red[16];
    if ((c & 63) == 0) red[c >> 6] = acc;
    __syncthreads();
    if (c < 64) {
        float v = (c < 16) ? red[c] : 0.f;
        #pragma unroll
        for (int m = 1; m < 16; m <<= 1) v += __shfl_xor(v, m, 64);
        if (c == 0) out[0] = v * (1.0f / (2.0f * (float)NPAIR));
    }
}

extern "C" void kernel_launch(void* const* d_in, const int* in_sizes, int n_in,
                              void* d_out, int out_size, void* d_ws, size_t ws_size,
                              hipStream_t stream) {
    const float* x = (const float*)d_in[0];
    char* ws = (char*)d_ws;
    unsigned short* partial = (unsigned short*)ws;        // 16*4096 bf16 = 128 KB
    float* posD = (float*)(ws + 131072);                  // 24 KB
    float* out = (float*)d_out;

    hipLaunchKernelGGL(main_kernel, dim3(512), dim3(512), 0, stream, x, partial, posD);
    hipLaunchKernelGGL(tail_kernel, dim3(1), dim3(1024), 0, stream, partial, posD, out);
}